// Round 4
// baseline (143.511 us; speedup 1.0000x reference)
//
#include <hip/hip_runtime.h>
#include <math.h>

// FilterBankConstructorND: K spheres of dim D+2=5, D=3, M=4 tetra rotations.
// Per sphere k:
//   p = normalize(spheres[k,:3] / (spheres[k,4]+eps)); q = normalize(ones_vec)
//   u = p+q;  a = 2/||u||^2;  w = q - a*(q.u)*u
//   R0 = I - a*u*u^T - 2*q*w^T          (two Householders composed; R0 @ p = q)
//   r = R0 @ s_top
//   for m: f = R0^T @ (T_m @ r);  fb[m] = (f0,f1,f2,s3,s4)
// Output: concat( R0 (K*9 floats), filter_banks (K*M*5 floats) )
//
// Memory-bound: ~20 MB read + ~121.6 MB write => ~24 us kernel roofline at
// 6.3 TB/s. v4: v3 minus the nontemporal-store builtin (v3 SIGABRT'd at
// runtime; NT was the only exotic codegen change and its expected gain is
// ~nil since plain streaming stores already hit 6.7 TB/s in the harness
// memsets). Keeps rcp/rsq intrinsics + float4 input staging + coalesced
// float4 output flush via LDS.

typedef float vf4 __attribute__((ext_vector_type(4)));

__global__ __launch_bounds__(256) void fbank_kernel(
    const float* __restrict__ spheres,
    const float* __restrict__ ones_vec,
    const float* __restrict__ tetra,
    float* __restrict__ out,
    int K)
{
    __shared__ float sT[36];
    __shared__ __align__(16) float in_s[256 * 5];    //  5 KB; read stride 5 (odd -> conflict-free)
    __shared__ __align__(16) float rot_s[256 * 9];   //  9 KB; stride 9 (odd -> conflict-free)
    __shared__ __align__(16) float fb_s[256 * 21];   // 21 KB; stride 21 (odd -> conflict-free)

    const int tid = threadIdx.x;

    // ---- stage inputs: 256 spheres = 1280 floats = 320 float4 (fully coalesced)
    {
        const size_t base  = (size_t)blockIdx.x * 1280;
        const size_t total = (size_t)K * 5;
        const vf4* spv = (const vf4*)(spheres + base);
        for (int i = tid; i < 320; i += 256) {
            if (base + (size_t)i * 4 + 4 <= total) {
                *(vf4*)&in_s[i * 4] = spv[i];
            }
        }
    }
    if (tid < 36) sT[tid] = tetra[tid];
    __syncthreads();

    const float s0 = in_s[tid * 5 + 0], s1 = in_s[tid * 5 + 1], s2 = in_s[tid * 5 + 2];
    const float s3 = in_s[tid * 5 + 3], s4 = in_s[tid * 5 + 4];

    // unembed + normalize center (1-ulp rcp/rsq: error << 0.113 threshold)
    const float inv = __builtin_amdgcn_rcpf(s4 + 1e-12f);
    const float c0 = s0 * inv, c1 = s1 * inv, c2 = s2 * inv;
    const float rn = __builtin_amdgcn_rsqf(c0 * c0 + c1 * c1 + c2 * c2);
    const float p0 = c0 * rn, p1 = c1 * rn, p2 = c2 * rn;

    // normalized ones vector (wave-uniform)
    float o0 = ones_vec[0], o1 = ones_vec[1], o2 = ones_vec[2];
    const float orn = __builtin_amdgcn_rsqf(o0 * o0 + o1 * o1 + o2 * o2);
    o0 *= orn; o1 *= orn; o2 *= orn;

    // R0 = I - a*u*u^T - 2*q*w^T,  u = p+q, a = 2/||u||^2, w = q - a*(q.u)*u
    const float u0 = p0 + o0, u1 = p1 + o1, u2 = p2 + o2;
    const float a  = 2.0f * __builtin_amdgcn_rcpf(u0 * u0 + u1 * u1 + u2 * u2);
    const float atq = a * (o0 * u0 + o1 * u1 + o2 * u2);
    const float w0 = o0 - atq * u0, w1 = o1 - atq * u1, w2 = o2 - atq * u2;

    const float uu[3] = {u0, u1, u2}, oo[3] = {o0, o1, o2}, ww[3] = {w0, w1, w2};
    float R[3][3];
#pragma unroll
    for (int i = 0; i < 3; ++i)
#pragma unroll
        for (int j = 0; j < 3; ++j)
            R[i][j] = ((i == j) ? 1.0f : 0.0f) - a * uu[i] * uu[j] - 2.0f * oo[i] * ww[j];

    // r = R0 @ s_top
    const float r0 = R[0][0] * s0 + R[0][1] * s1 + R[0][2] * s2;
    const float r1 = R[1][0] * s0 + R[1][1] * s1 + R[1][2] * s2;
    const float r2 = R[2][0] * s0 + R[2][1] * s1 + R[2][2] * s2;

    // stage R into LDS
#pragma unroll
    for (int i = 0; i < 3; ++i)
#pragma unroll
        for (int j = 0; j < 3; ++j)
            rot_s[tid * 9 + i * 3 + j] = R[i][j];

    // filter banks: f = R0^T @ (T_m @ r)
#pragma unroll
    for (int m = 0; m < 4; ++m) {
        const float* T = sT + m * 9;
        const float g0 = T[0] * r0 + T[1] * r1 + T[2] * r2;
        const float g1 = T[3] * r0 + T[4] * r1 + T[5] * r2;
        const float g2 = T[6] * r0 + T[7] * r1 + T[8] * r2;
        fb_s[tid * 21 + m * 5 + 0] = R[0][0] * g0 + R[1][0] * g1 + R[2][0] * g2;
        fb_s[tid * 21 + m * 5 + 1] = R[0][1] * g0 + R[1][1] * g1 + R[2][1] * g2;
        fb_s[tid * 21 + m * 5 + 2] = R[0][2] * g0 + R[1][2] * g1 + R[2][2] * g2;
        fb_s[tid * 21 + m * 5 + 3] = s3;
        fb_s[tid * 21 + m * 5 + 4] = s4;
    }
    __syncthreads();

    // ---- flush rotations: 256*9 = 2304 floats = 576 float4, contiguous & coalesced
    {
        float* rot_out = out + (size_t)blockIdx.x * 2304;
        const long long lim = (long long)K * 9 - (long long)blockIdx.x * 2304;
        for (int i = tid; i < 576; i += 256) {
            if ((long long)i * 4 + 3 < lim) {
                vf4 v = *(const vf4*)&rot_s[i * 4];
                *(vf4*)(rot_out + (size_t)i * 4) = v;
            }
        }
    }
    // ---- flush filter banks: 256*20 = 5120 floats = 1280 float4
    {
        float* fb_out = out + (size_t)K * 9 + (size_t)blockIdx.x * 5120;
        const long long lim = (long long)K * 20 - (long long)blockIdx.x * 5120;
        for (int i = tid; i < 1280; i += 256) {
            const int f = i * 4;
            if ((long long)f + 3 < lim) {
                vf4 v;
                v.x = fb_s[((f + 0) / 20) * 21 + (f + 0) % 20];
                v.y = fb_s[((f + 1) / 20) * 21 + (f + 1) % 20];
                v.z = fb_s[((f + 2) / 20) * 21 + (f + 2) % 20];
                v.w = fb_s[((f + 3) / 20) * 21 + (f + 3) % 20];
                *(vf4*)(fb_out + f) = v;
            }
        }
    }
}

extern "C" void kernel_launch(void* const* d_in, const int* in_sizes, int n_in,
                              void* d_out, int out_size, void* d_ws, size_t ws_size,
                              hipStream_t stream) {
    const float* spheres  = (const float*)d_in[0];   // (K, 5)
    const float* ones_vec = (const float*)d_in[1];   // (3,)
    const float* tetra    = (const float*)d_in[2];   // (4, 3, 3)
    float* out = (float*)d_out;                      // K*9 rot, then K*4*5 fb
    const int K = in_sizes[0] / 5;
    const int grid = (K + 255) / 256;
    fbank_kernel<<<grid, 256, 0, stream>>>(spheres, ones_vec, tetra, out, K);
}

// Round 5
// 140.201 us; speedup vs baseline: 1.0236x; 1.0236x over previous
//
#include <hip/hip_runtime.h>
#include <math.h>

// FilterBankConstructorND: K spheres of dim D+2=5, D=3, M=4 tetra rotations.
//   p = normalize(spheres[k,:3] / (spheres[k,4]+eps)); q = normalize(ones_vec)
//   u = p+q;  a = 2/||u||^2;  w = q - a*(q.u)*u
//   R0 = I - a*u*u^T - 2*q*w^T          (two Householders composed; R0 @ p = q)
//   r = R0 @ s_top;  for m: f = R0^T @ (T_m @ r);  fb[m] = (f0,f1,f2,s3,s4)
// Output: concat( R0 (K*9 floats), filter_banks (K*M*5 floats) )
//
// Memory-bound: ~20 MB read + ~121.6 MB write => ~23 us kernel roofline.
// v5: LDS union (input staging aliases fb buffer) 35.3->30.1 KB => 5 blocks/CU
// (20 waves/CU vs 16); uniform full-block fast path (no per-element bounds
// checks); merged rot+fb flush loop (stores issue earlier). Disambiguates
// latency-bound (expect -15us) vs already-BW-bound (expect null => roofline).

typedef float vf4 __attribute__((ext_vector_type(4)));

__global__ __launch_bounds__(256) void fbank_kernel(
    const float* __restrict__ spheres,
    const float* __restrict__ ones_vec,
    const float* __restrict__ tetra,
    float* __restrict__ out,
    int K)
{
    __shared__ float sT[36];
    __shared__ __align__(16) float rot_s[256 * 9];   //  9 KB; stride 9 (odd -> 2-way, free)
    __shared__ __align__(16) float u_s[256 * 21];    // 21 KB union: in-stage (1280 f) then fb (stride 21)

    const int tid = threadIdx.x;
    const size_t base  = (size_t)blockIdx.x * 1280;
    const size_t total = (size_t)K * 5;
    const bool full = (base + 1280 <= total);        // wave-uniform

    // ---- stage inputs: 256 spheres = 1280 floats = 320 float4 (coalesced)
    {
        const vf4* spv = (const vf4*)(spheres + base);
        if (full) {
            *(vf4*)&u_s[tid * 4] = spv[tid];
            if (tid < 64) *(vf4*)&u_s[(256 + tid) * 4] = spv[256 + tid];
        } else {
            for (int i = tid; i < 320; i += 256)
                if (base + (size_t)i * 4 + 4 <= total)
                    *(vf4*)&u_s[i * 4] = spv[i];
        }
    }
    if (tid < 36) sT[tid] = tetra[tid];
    __syncthreads();

    // read my sphere into registers (stride 5, odd -> 2-way, free)
    const float s0 = u_s[tid * 5 + 0], s1 = u_s[tid * 5 + 1], s2 = u_s[tid * 5 + 2];
    const float s3 = u_s[tid * 5 + 3], s4 = u_s[tid * 5 + 4];

    // unembed + normalize center (1-ulp rcp/rsq: error << 0.113 threshold)
    const float inv = __builtin_amdgcn_rcpf(s4 + 1e-12f);
    const float c0 = s0 * inv, c1 = s1 * inv, c2 = s2 * inv;
    const float rn = __builtin_amdgcn_rsqf(c0 * c0 + c1 * c1 + c2 * c2);
    const float p0 = c0 * rn, p1 = c1 * rn, p2 = c2 * rn;

    // normalized ones vector (wave-uniform)
    float o0 = ones_vec[0], o1 = ones_vec[1], o2 = ones_vec[2];
    const float orn = __builtin_amdgcn_rsqf(o0 * o0 + o1 * o1 + o2 * o2);
    o0 *= orn; o1 *= orn; o2 *= orn;

    // R0 = I - a*u*u^T - 2*q*w^T
    const float u0 = p0 + o0, u1 = p1 + o1, u2 = p2 + o2;
    const float a  = 2.0f * __builtin_amdgcn_rcpf(u0 * u0 + u1 * u1 + u2 * u2);
    const float atq = a * (o0 * u0 + o1 * u1 + o2 * u2);
    const float w0 = o0 - atq * u0, w1 = o1 - atq * u1, w2 = o2 - atq * u2;

    const float uu[3] = {u0, u1, u2}, oo[3] = {o0, o1, o2}, ww[3] = {w0, w1, w2};
    float R[3][3];
#pragma unroll
    for (int i = 0; i < 3; ++i)
#pragma unroll
        for (int j = 0; j < 3; ++j)
            R[i][j] = ((i == j) ? 1.0f : 0.0f) - a * uu[i] * uu[j] - 2.0f * oo[i] * ww[j];

    // r = R0 @ s_top; filter banks f = R0^T @ (T_m @ r) -> registers
    const float r0 = R[0][0] * s0 + R[0][1] * s1 + R[0][2] * s2;
    const float r1 = R[1][0] * s0 + R[1][1] * s1 + R[1][2] * s2;
    const float r2 = R[2][0] * s0 + R[2][1] * s1 + R[2][2] * s2;

    float f[12];
#pragma unroll
    for (int m = 0; m < 4; ++m) {
        const float* T = sT + m * 9;
        const float g0 = T[0] * r0 + T[1] * r1 + T[2] * r2;
        const float g1 = T[3] * r0 + T[4] * r1 + T[5] * r2;
        const float g2 = T[6] * r0 + T[7] * r1 + T[8] * r2;
        f[m * 3 + 0] = R[0][0] * g0 + R[1][0] * g1 + R[2][0] * g2;
        f[m * 3 + 1] = R[0][1] * g0 + R[1][1] * g1 + R[2][1] * g2;
        f[m * 3 + 2] = R[0][2] * g0 + R[1][2] * g1 + R[2][2] * g2;
    }

    __syncthreads();  // all u_s input reads complete before fb overwrites it

    // stage R (stride 9) and fb (stride 21, odd -> 2-way, free)
#pragma unroll
    for (int i = 0; i < 3; ++i)
#pragma unroll
        for (int j = 0; j < 3; ++j)
            rot_s[tid * 9 + i * 3 + j] = R[i][j];
#pragma unroll
    for (int m = 0; m < 4; ++m) {
        u_s[tid * 21 + m * 5 + 0] = f[m * 3 + 0];
        u_s[tid * 21 + m * 5 + 1] = f[m * 3 + 1];
        u_s[tid * 21 + m * 5 + 2] = f[m * 3 + 2];
        u_s[tid * 21 + m * 5 + 3] = s3;
        u_s[tid * 21 + m * 5 + 4] = s4;
    }
    __syncthreads();

    // ---- merged flush: 576 rot float4 + 1280 fb float4 = 1856, coalesced
    float* rot_out = out + (size_t)blockIdx.x * 2304;
    float* fb_out  = out + (size_t)K * 9 + (size_t)blockIdx.x * 5120;
    if (full) {
        for (int i = tid; i < 1856; i += 256) {
            if (i < 576) {
                *(vf4*)(rot_out + (size_t)i * 4) = *(const vf4*)&rot_s[i * 4];
            } else {
                const int fo = (i - 576) * 4;
                vf4 v;
                v.x = u_s[((fo + 0) / 20) * 21 + (fo + 0) % 20];
                v.y = u_s[((fo + 1) / 20) * 21 + (fo + 1) % 20];
                v.z = u_s[((fo + 2) / 20) * 21 + (fo + 2) % 20];
                v.w = u_s[((fo + 3) / 20) * 21 + (fo + 3) % 20];
                *(vf4*)(fb_out + fo) = v;
            }
        }
    } else {
        const long long limr = (long long)K * 9 - (long long)blockIdx.x * 2304;
        for (int i = tid; i < 576; i += 256)
            if ((long long)i * 4 + 3 < limr)
                *(vf4*)(rot_out + (size_t)i * 4) = *(const vf4*)&rot_s[i * 4];
        const long long limf = (long long)K * 20 - (long long)blockIdx.x * 5120;
        for (int i = tid; i < 1280; i += 256) {
            const int fo = i * 4;
            if ((long long)fo + 3 < limf) {
                vf4 v;
                v.x = u_s[((fo + 0) / 20) * 21 + (fo + 0) % 20];
                v.y = u_s[((fo + 1) / 20) * 21 + (fo + 1) % 20];
                v.z = u_s[((fo + 2) / 20) * 21 + (fo + 2) % 20];
                v.w = u_s[((fo + 3) / 20) * 21 + (fo + 3) % 20];
                *(vf4*)(fb_out + fo) = v;
            }
        }
    }
}

extern "C" void kernel_launch(void* const* d_in, const int* in_sizes, int n_in,
                              void* d_out, int out_size, void* d_ws, size_t ws_size,
                              hipStream_t stream) {
    const float* spheres  = (const float*)d_in[0];   // (K, 5)
    const float* ones_vec = (const float*)d_in[1];   // (3,)
    const float* tetra    = (const float*)d_in[2];   // (4, 3, 3)
    float* out = (float*)d_out;                      // K*9 rot, then K*4*5 fb
    const int K = in_sizes[0] / 5;
    const int grid = (K + 255) / 256;
    fbank_kernel<<<grid, 256, 0, stream>>>(spheres, ones_vec, tetra, out, K);
}